// Round 1
// baseline (542.169 us; speedup 1.0000x reference)
//
#include <hip/hip_runtime.h>
#include <cstdint>

#define NN 100000
#define EE 1600000
#define IN_F 512
#define HID_F 256
#define OUT_F 32

typedef float f32x4 __attribute__((ext_vector_type(4)));
typedef short s16x8 __attribute__((ext_vector_type(8)));
typedef unsigned short u16;

static __device__ __forceinline__ u16 f2bf(float f) {
  uint32_t u = __builtin_bit_cast(uint32_t, f);
  u += 0x7FFFu + ((u >> 16) & 1u);   // round-to-nearest-even
  return (u16)(u >> 16);
}

// ---------------- weight prep: transpose + bf16 + LDS-swizzle pre-bake ----------------
// W1S layout: per k-tile kt (64 k), linear bytes L = n*128 + kb' where the element
// stored at kb' is k = kt*64 + (kb' ^ ((n&7)<<4))/2, i.e. a straight linear copy into
// LDS yields the swizzled [n][k] layout the MFMA B-fragment reads expect.
__global__ void k_w1prep(const float* __restrict__ w1, u16* __restrict__ w1s) {
  int g = blockIdx.x * 256 + threadIdx.x;           // 512*256 elements
  if (g >= IN_F * HID_F) return;
  int kt = g >> 14;                                  // /16384 (64*256)
  int r  = g & 16383;
  int n  = r >> 6;
  int jp = r & 63;
  int kb = (jp * 2) ^ ((n & 7) << 4);
  int k  = kt * 64 + (kb >> 1);
  w1s[g] = f2bf(w1[k * HID_F + n]);
}

// W2S: [n=32][k=256] bf16, swizzled rows of 512B
__global__ void k_w2prep(const float* __restrict__ w2, u16* __restrict__ w2s) {
  int g = blockIdx.x * 256 + threadIdx.x;           // 32*256 elements
  if (g >= HID_F * OUT_F) return;
  int n  = g >> 8;
  int jp = g & 255;
  int kb = (jp * 2) ^ ((n & 7) << 4);
  int j  = kb >> 1;
  w2s[g] = f2bf(w2[j * OUT_F + n]);
}

// ---------------- graph prep: in-degree count, scan, CSR fill ----------------
__global__ void k_count(const int* __restrict__ col, int* __restrict__ cnt) {
  int e = blockIdx.x * 256 + threadIdx.x;
  if (e < EE) {
    unsigned c = (unsigned)col[e];
    if (c < NN) atomicAdd(&cnt[c], 1);
  }
}

__global__ void k_scan1(const int* __restrict__ cnt, int* __restrict__ offs,
                        int* __restrict__ bsum) {
  __shared__ int s[256];
  int i = blockIdx.x * 256 + threadIdx.x;
  int v = (i < NN) ? cnt[i] : 0;
  s[threadIdx.x] = v;
  __syncthreads();
  for (int d = 1; d < 256; d <<= 1) {
    int t = (threadIdx.x >= d) ? s[threadIdx.x - d] : 0;
    __syncthreads();
    s[threadIdx.x] += t;
    __syncthreads();
  }
  if (i < NN) offs[i + 1] = s[threadIdx.x];
  if (threadIdx.x == 0) bsum[blockIdx.x] = s[255];
}

__global__ void k_scan2(int* __restrict__ bsum) {
  __shared__ int s[512];
  int t = threadIdx.x;
  int v = (t < 391) ? bsum[t] : 0;
  s[t] = v;
  __syncthreads();
  for (int d = 1; d < 512; d <<= 1) {
    int u = (t >= d) ? s[t - d] : 0;
    __syncthreads();
    s[t] += u;
    __syncthreads();
  }
  if (t < 391) bsum[t] = s[t];
}

__global__ void k_scan3(const int* __restrict__ cnt, int* __restrict__ offs,
                        const int* __restrict__ bsum, int* __restrict__ cur,
                        float* __restrict__ dis) {
  int i = blockIdx.x * 256 + threadIdx.x;
  if (i >= NN) return;
  int add = blockIdx.x ? bsum[blockIdx.x - 1] : 0;
  int inc = offs[i + 1] + add;
  offs[i + 1] = inc;
  cur[i] = inc - cnt[i];
  dis[i] = rsqrtf((float)cnt[i] + 1.0f);   // deg includes self loop
  if (i == 0) offs[0] = 0;
}

__global__ void k_fill(const int* __restrict__ rowi, const int* __restrict__ coli,
                       int* __restrict__ cur, int* __restrict__ csr) {
  int e = blockIdx.x * 256 + threadIdx.x;
  if (e < EE) {
    unsigned c = (unsigned)coli[e];
    if (c < NN) {
      int p = atomicAdd(&cur[c], 1);
      csr[p] = rowi[e];
    }
  }
}

// ---------------- fused MLP: h = relu(x@W1+b1)@W2 + b2 ----------------
__global__ __launch_bounds__(512) void k_mlp(
    const float* __restrict__ x, const float* __restrict__ b1,
    const float* __restrict__ b2, const u16* __restrict__ w1s,
    const u16* __restrict__ w2s, float* __restrict__ hout) {
  __shared__ char smem[81920];
  char* aL  = smem;           // [128][128B] swizzled bf16 A tile (K-loop)
  char* bL  = smem + 16384;   // [256][128B] swizzled bf16 B tile (K-loop)
  char* h1L = smem;           // [128][512B] swizzled bf16 h1    (post-loop)
  char* w2L = smem + 65536;   // [32][512B]  swizzled bf16 W2^T

  const int tid  = threadIdx.x;
  const int lane = tid & 63;
  const int wid  = tid >> 6;   // 0..7
  const int wm   = wid >> 2;   // 0..1  (64-row half)
  const int wn   = wid & 3;    // 0..3  (64-col quarter)
  const int l16  = lane & 15;
  const int lq   = lane >> 4;  // 0..3
  const int row0 = blockIdx.x * 128;

  // stage W2 (16 KB) once
  {
    const char* src = (const char*)w2s;
    #pragma unroll
    for (int p = 0; p < 2; ++p) {
      int off = (p * 512 + tid) * 16;
      *(f32x4*)(w2L + off) = *(const f32x4*)(src + off);
    }
  }

  const f32x4 zf = {0.f, 0.f, 0.f, 0.f};
  f32x4 acc[4][4];
  #pragma unroll
  for (int i = 0; i < 4; ++i)
    #pragma unroll
    for (int j = 0; j < 4; ++j) acc[i][j] = zf;

  for (int kt = 0; kt < IN_F / 64; ++kt) {
    __syncthreads();
    // stage A: 128x64 fp32 -> bf16, swizzled writes
    #pragma unroll
    for (int p = 0; p < 4; ++p) {
      int v   = p * 512 + tid;     // float4 index, 2048 total
      int row = v >> 4;            // 0..127
      int f4  = v & 15;
      int grow = row0 + row;
      f32x4 xv = zf;
      if (grow < NN)
        xv = *(const f32x4*)(x + (size_t)grow * IN_F + kt * 64 + f4 * 4);
      uint32_t lo = (uint32_t)f2bf(xv.x) | ((uint32_t)f2bf(xv.y) << 16);
      uint32_t hi = (uint32_t)f2bf(xv.z) | ((uint32_t)f2bf(xv.w) << 16);
      uint64_t wv = (uint64_t)lo | ((uint64_t)hi << 32);
      int kb = (f4 * 8) ^ ((row & 7) << 4);
      *(uint64_t*)(aL + row * 128 + kb) = wv;
    }
    // stage B: linear 32KB copy (swizzle pre-baked in W1S)
    {
      const char* src = (const char*)w1s + kt * 32768;
      #pragma unroll
      for (int p = 0; p < 4; ++p) {
        int off = (p * 512 + tid) * 16;
        *(f32x4*)(bL + off) = *(const f32x4*)(src + off);
      }
    }
    __syncthreads();
    #pragma unroll
    for (int ks = 0; ks < 2; ++ks) {
      int kb = ks * 64 + lq * 16;
      s16x8 af[4], bf[4];
      #pragma unroll
      for (int fm = 0; fm < 4; ++fm) {
        int row = wm * 64 + fm * 16 + l16;
        af[fm] = *(const s16x8*)(aL + row * 128 + (kb ^ ((row & 7) << 4)));
      }
      #pragma unroll
      for (int fn = 0; fn < 4; ++fn) {
        int n = wn * 64 + fn * 16 + l16;
        bf[fn] = *(const s16x8*)(bL + n * 128 + (kb ^ ((n & 7) << 4)));
      }
      #pragma unroll
      for (int fm = 0; fm < 4; ++fm)
        #pragma unroll
        for (int fn = 0; fn < 4; ++fn)
          acc[fm][fn] = __builtin_amdgcn_mfma_f32_16x16x32_bf16(
              af[fm], bf[fn], acc[fm][fn], 0, 0, 0);
    }
  }

  // bias + relu -> h1L (bf16, swizzled)
  float b1v[4];
  #pragma unroll
  for (int fn = 0; fn < 4; ++fn) b1v[fn] = b1[wn * 64 + fn * 16 + l16];

  __syncthreads();   // all waves done reading aL/bL
  #pragma unroll
  for (int fm = 0; fm < 4; ++fm) {
    #pragma unroll
    for (int fn = 0; fn < 4; ++fn) {
      int col = wn * 64 + fn * 16 + l16;
      #pragma unroll
      for (int r = 0; r < 4; ++r) {
        int row = wm * 64 + fm * 16 + lq * 4 + r;
        float v = acc[fm][fn][r] + b1v[fn];
        v = fmaxf(v, 0.f);
        *(u16*)(h1L + row * 512 + ((col * 2) ^ ((row & 7) << 4))) = f2bf(v);
      }
    }
  }
  __syncthreads();

  // GEMM2: [128x256] @ [256x32], each wave owns 16 rows
  f32x4 acc2[2];
  acc2[0] = zf; acc2[1] = zf;
  const int arow = wid * 16 + l16;
  #pragma unroll
  for (int ks = 0; ks < 8; ++ks) {
    int kb = ks * 64 + lq * 16;
    s16x8 af = *(const s16x8*)(h1L + arow * 512 + (kb ^ ((arow & 7) << 4)));
    #pragma unroll
    for (int fn = 0; fn < 2; ++fn) {
      int bn = fn * 16 + l16;
      s16x8 bf = *(const s16x8*)(w2L + bn * 512 + (kb ^ ((bn & 7) << 4)));
      acc2[fn] = __builtin_amdgcn_mfma_f32_16x16x32_bf16(af, bf, acc2[fn], 0, 0, 0);
    }
  }
  #pragma unroll
  for (int fn = 0; fn < 2; ++fn) {
    #pragma unroll
    for (int r = 0; r < 4; ++r) {
      int row = row0 + wid * 16 + lq * 4 + r;
      int col = fn * 16 + l16;
      if (row < NN) hout[(size_t)row * 32 + col] = acc2[fn][r] + b2[col];
    }
  }
}

// ---------------- propagation step: xout = h + prox_l21(A_hat@xin - h) ----------------
// one wave per node: lanes = 32 features x 2 edge slots
__global__ __launch_bounds__(256) void k_prop(
    const float* __restrict__ xin, const float* __restrict__ hh,
    float* __restrict__ xout, const float* __restrict__ dis,
    const int* __restrict__ offs, const int* __restrict__ csr) {
  int w = blockIdx.x * 4 + (threadIdx.x >> 6);
  if (w >= NN) return;
  int lane = threadIdx.x & 63;
  int f    = lane & 31;
  int half = lane >> 5;
  int s = offs[w], e = offs[w + 1];
  float acc = 0.f;
  for (int j = s + half; j < e; j += 2) {
    int src = csr[j];
    acc += dis[src] * xin[(size_t)src * 32 + f];
  }
  acc += __shfl_xor(acc, 32, 64);
  float di = dis[w];
  float ax = di * acc + di * di * xin[(size_t)w * 32 + f];  // + self loop
  float hv = hh[(size_t)w * 32 + f];
  float d  = ax - hv;                                        // y - hh (y == A_hat@xk)
  float rn2 = d * d;
  #pragma unroll
  for (int m = 16; m >= 1; m >>= 1) rn2 += __shfl_xor(rn2, m, 64);
  float rn = sqrtf(rn2);
  float sc = (rn > 0.f) ? fmaxf(rn - 0.5f, 0.f) / rn : 0.f;  // lam*gamma = 0.5
  if (half == 0) xout[(size_t)w * 32 + f] = hv + sc * d;
}

// ---------------- launch ----------------
extern "C" void kernel_launch(void* const* d_in, const int* in_sizes, int n_in,
                              void* d_out, int out_size, void* d_ws, size_t ws_size,
                              hipStream_t stream) {
  const float* x  = (const float*)d_in[0];
  const float* W1 = (const float*)d_in[1];
  const float* b1 = (const float*)d_in[2];
  const float* W2 = (const float*)d_in[3];
  const float* b2 = (const float*)d_in[4];
  const int*   ei = (const int*)d_in[5];   // [2][E] int32

  char* ws = (char*)d_ws;
  float* h    = (float*)(ws);                  // 12.8 MB
  float* bufA = (float*)(ws + 12800000);       // 12.8 MB
  int*   csr  = (int*)  (ws + 25600000);       // 6.4 MB
  int*   cnt  = (int*)  (ws + 32000000);       // 400 KB
  int*   offs = (int*)  (ws + 32400000);       // 400 KB (N+1)
  int*   cur  = (int*)  (ws + 32800016);       // 400 KB
  int*   bsum = (int*)  (ws + 33200016);       // 2 KB
  float* dis  = (float*)(ws + 33202064);       // 400 KB
  u16*   w1s  = (u16*)  (ws + 33602064);       // 256 KB
  u16*   w2s  = (u16*)  (ws + 33864208);       // 16 KB

  hipMemsetAsync(cnt, 0, NN * sizeof(int), stream);
  k_w1prep<<<512, 256, 0, stream>>>(W1, w1s);
  k_w2prep<<<32, 256, 0, stream>>>(W2, w2s);
  k_count<<<(EE + 255) / 256, 256, 0, stream>>>(ei + EE, cnt);
  k_scan1<<<391, 256, 0, stream>>>(cnt, offs, bsum);
  k_scan2<<<1, 512, 0, stream>>>(bsum);
  k_scan3<<<391, 256, 0, stream>>>(cnt, offs, bsum, cur, dis);
  k_fill<<<(EE + 255) / 256, 256, 0, stream>>>(ei, ei + EE, cur, csr);
  k_mlp<<<(NN + 127) / 128, 512, 0, stream>>>(x, b1, b2, w1s, w2s, h);

  float* out = (float*)d_out;
  k_prop<<<(NN + 3) / 4, 256, 0, stream>>>(h,    h, out,  dis, offs, csr);
  k_prop<<<(NN + 3) / 4, 256, 0, stream>>>(out,  h, bufA, dis, offs, csr);
  k_prop<<<(NN + 3) / 4, 256, 0, stream>>>(bufA, h, out,  dis, offs, csr);
}